// Round 5
// baseline (1156.991 us; speedup 1.0000x reference)
//
#include <hip/hip_runtime.h>
#include <stdint.h>

#define BB 64      // batch
#define TT 64      // time steps
#define NIN 128
#define NHID 256
#define NOUT 32
#define BPS 4                  // blocks per sample (j-sliced)
#define NBLK (BB * BPS)        // 256 = one block per CU
#define NTHR 1024
#define JS 64                  // j-columns per block

#define SIG_NEU 0.05f
#define SIG_SYN 0.002f

// workspace layout (bytes)
#define FLAG_OFF    0
#define FLAG_STRIDE 32                                // u32s -> 128B per flag line
#define FLAG_BYTES  (BB * BPS * FLAG_STRIDE * 4)      // 32 KB, memset(0) per launch
#define HPUB_OFF    FLAG_BYTES                        // float[2][BB][NHID] = 128 KB

#define HID_LIST_SZ ((size_t)BB * TT * NHID)          // 1048576
#define OUT_LIST_SZ ((size_t)BB * TT * NOUT)          // 131072

__device__ __forceinline__ uint32_t rotl32(uint32_t v, int s) {
  return (v << s) | (v >> (32 - s));
}

// JAX threefry2x32 (5 groups of 4 rounds)
__device__ __forceinline__ void tf2x32(uint32_t k0, uint32_t k1, uint32_t x0, uint32_t x1,
                                       uint32_t& o0, uint32_t& o1) {
  const uint32_t k2 = k0 ^ k1 ^ 0x1BD11BDAu;
  x0 += k0; x1 += k1;
  x0 += x1; x1 = rotl32(x1,13); x1 ^= x0;
  x0 += x1; x1 = rotl32(x1,15); x1 ^= x0;
  x0 += x1; x1 = rotl32(x1,26); x1 ^= x0;
  x0 += x1; x1 = rotl32(x1, 6); x1 ^= x0;
  x0 += k1; x1 += k2 + 1u;
  x0 += x1; x1 = rotl32(x1,17); x1 ^= x0;
  x0 += x1; x1 = rotl32(x1,29); x1 ^= x0;
  x0 += x1; x1 = rotl32(x1,16); x1 ^= x0;
  x0 += x1; x1 = rotl32(x1,24); x1 ^= x0;
  x0 += k2; x1 += k0 + 2u;
  x0 += x1; x1 = rotl32(x1,13); x1 ^= x0;
  x0 += x1; x1 = rotl32(x1,15); x1 ^= x0;
  x0 += x1; x1 = rotl32(x1,26); x1 ^= x0;
  x0 += x1; x1 = rotl32(x1, 6); x1 ^= x0;
  x0 += k0; x1 += k1 + 3u;
  x0 += x1; x1 = rotl32(x1,17); x1 ^= x0;
  x0 += x1; x1 = rotl32(x1,29); x1 ^= x0;
  x0 += x1; x1 = rotl32(x1,16); x1 ^= x0;
  x0 += x1; x1 = rotl32(x1,24); x1 ^= x0;
  x0 += k1; x1 += k2 + 4u;
  x0 += x1; x1 = rotl32(x1,13); x1 ^= x0;
  x0 += x1; x1 = rotl32(x1,15); x1 ^= x0;
  x0 += x1; x1 = rotl32(x1,26); x1 ^= x0;
  x0 += x1; x1 = rotl32(x1, 6); x1 ^= x0;
  x0 += k2; x1 += k0 + 5u;
  o0 = x0; o1 = x1;
}

// partitionable random_bits(32) element idx -> N(0,1) exactly as jax.random.normal
__device__ __forceinline__ float tf_normal(uint32_t k0, uint32_t k1, uint32_t idx) {
  uint32_t o0, o1;
  tf2x32(k0, k1, 0u, idx, o0, o1);
  const uint32_t bits = o0 ^ o1;
  const float u = __uint_as_float((bits >> 9) | 0x3f800000u) - 1.0f;  // [0,1)
  float x = fmaf(u, 2.0f, -0.99999994f);                              // [-1+eps, 1)
  x = fmaxf(x, -0.99999994f);
  // XLA ErfInv f32 (Giles)
  const float w = -__logf(fmaf(-x, x, 1.0f));
  float p;
  if (w < 5.0f) {
    const float q = w - 2.5f;
    p = 2.81022636e-08f;
    p = fmaf(p, q, 3.43273939e-07f);
    p = fmaf(p, q, -3.5233877e-06f);
    p = fmaf(p, q, -4.39150654e-06f);
    p = fmaf(p, q, 0.00021858087f);
    p = fmaf(p, q, -0.00125372503f);
    p = fmaf(p, q, -0.00417768164f);
    p = fmaf(p, q, 0.246640727f);
    p = fmaf(p, q, 1.50140941f);
  } else {
    const float q = sqrtf(w) - 3.0f;
    p = -0.000200214257f;
    p = fmaf(p, q, 0.000100950558f);
    p = fmaf(p, q, 0.00134934322f);
    p = fmaf(p, q, -0.00367342844f);
    p = fmaf(p, q, 0.00573950773f);
    p = fmaf(p, q, -0.0076224613f);
    p = fmaf(p, q, 0.00943887047f);
    p = fmaf(p, q, 1.00167406f);
    p = fmaf(p, q, 2.83297682f);
  }
  return 1.41421356f * (p * x);  // sqrt(2)*erfinv
}

#define SPIN(slice, want)                                                         \
  do {                                                                            \
    uint32_t* fp_ = &flags[((b) * BPS + (slice)) * FLAG_STRIDE];                  \
    for (int it_ = 0; it_ < 1000000; ++it_) {                                     \
      if (__hip_atomic_load(fp_, __ATOMIC_RELAXED, __HIP_MEMORY_SCOPE_AGENT) >=   \
          (uint32_t)(want)) break;                                                \
      __builtin_amdgcn_s_sleep(1);                                                \
    }                                                                             \
  } while (0)

__global__ __launch_bounds__(NTHR, 4) void rnn_kernel(
    const float* __restrict__ xin, const float* __restrict__ h0,
    const float* __restrict__ w_in, const float* __restrict__ w_hh,
    const float* __restrict__ b_hh, const float* __restrict__ w_out,
    const float* __restrict__ alpha, const float* __restrict__ beta,
    float* __restrict__ out, char* __restrict__ ws)
{
  __shared__ __align__(16) float wos[8 * 260];   // w_out slice (8 rows), +4 pad
  __shared__ __align__(16) float h_s[NHID];
  __shared__ __align__(16) float a_s[NHID];
  __shared__ __align__(16) float xt_s[NIN];
  __shared__ float stat_s[JS];
  __shared__ float djact_s[JS];
  __shared__ uint32_t keys_s[TT * 4];

  const int tid = threadIdx.x;
  const int blk = blockIdx.x;
  const int b   = blk & 63;      // sample; siblings blk = s*64+b are == b (mod 8) -> same XCD
  const int s   = blk >> 6;      // 0..3 j-slice index

  uint32_t* flags = (uint32_t*)(ws + FLAG_OFF);
  float*    hpub  = (float*)(ws + HPUB_OFF);

  // ---------------- init ----------------
  if (tid < TT) {
    uint32_t ka, kb, t0, t1;
    tf2x32(0u, 42u, 0u, (uint32_t)tid, ka, kb);   // keys[t] = split(key(42),64)[t]
    tf2x32(ka, kb, 0u, 0u, t0, t1);               // k1 (neural)
    keys_s[tid * 4 + 0] = t0; keys_s[tid * 4 + 1] = t1;
    tf2x32(ka, kb, 0u, 1u, t0, t1);               // k2 (synaptic)
    keys_s[tid * 4 + 2] = t0; keys_s[tid * 4 + 3] = t1;
  }
  if (tid < NHID) {
    const float hv = h0[b * NHID + tid];
    h_s[tid] = hv;
    a_s[tid] = tanhf(hv);
  }
  #pragma unroll
  for (int e = 0; e < 2; ++e) {                   // w_out slice -> LDS
    const int idx = tid + e * NTHR;
    const int r = idx >> 8, c = idx & 255;
    wos[r * 260 + c] = w_out[(s * 8 + r) * NHID + c];
  }

  // thread mapping: jl = row/column index (0..63), q = 16-lane slice (0..15)
  const int q  = tid & 15;
  const int jl = tid >> 4;           // 0..63
  const int jg = s * JS + jl;        // global j / GEMV row
  const float bj  = beta[jg];
  const float sbj = SIG_SYN * sqrtf(bj);
  const uint32_t idxb = ((uint32_t)b << 16) | ((uint32_t)q << 8) | (uint32_t)jg;

  // loop-invariant GEMV weights in registers (24 VGPR)
  float4 whr[4], winr[2];
  #pragma unroll
  for (int k = 0; k < 4; ++k)
    whr[k] = *(const float4*)(w_hh + (size_t)jg * NHID + q * 16 + k * 4);
  #pragma unroll
  for (int k = 0; k < 2; ++k)
    winr[k] = *(const float4*)(w_in + (size_t)jg * NIN + q * 8 + k * 4);
  const float bias = b_hh[jg];

  // h-update consts (tid<64)
  float r_al = 0.f, r_om = 0.f, r_ns = 0.f;
  uint32_t hnidx = 0;
  if (tid < JS) {
    r_al = alpha[s * JS + tid];
    r_om = 1.0f - r_al;
    r_ns = SIG_NEU * sqrtf(r_al);
    hnidx = (uint32_t)(b * NHID + s * JS + tid);
  }

  float d[16];
  #pragma unroll
  for (int r = 0; r < 16; ++r) d[r] = 0.0f;
  float n[16];
  float hn = 0.0f;

  __syncthreads();

  // -------- prologue: RNG for t=0, x_0 --------
  {
    const uint32_t k2a = __builtin_amdgcn_readfirstlane(keys_s[2]);
    const uint32_t k2b = __builtin_amdgcn_readfirstlane(keys_s[3]);
    #pragma unroll
    for (int r = 0; r < 16; ++r)
      n[r] = tf_normal(k2a, k2b, idxb + ((uint32_t)r << 12));
    if (tid < JS) {
      const uint32_t k1a = __builtin_amdgcn_readfirstlane(keys_s[0]);
      const uint32_t k1b = __builtin_amdgcn_readfirstlane(keys_s[1]);
      hn = tf_normal(k1a, k1b, hnidx);
    }
    if (tid < NIN) xt_s[tid] = xin[((size_t)b * TT) * NIN + tid];
  }
  __syncthreads();

  const int wv = tid >> 6;     // wave id 0..15
  const int ln = tid & 63;

  for (int t = 0; t < TT; ++t) {
    const int par = t & 1;

    // ================ P1: dj + GEMV + outproj(t-1) ================
    const float aj = a_s[jg];
    float pd = 0.0f;
    #pragma unroll
    for (int r = 0; r < 16; ++r) {
      const float ai = a_s[q + 16 * r];            // i = q + 16r
      pd = fmaf(ai, d[r], pd);                     // uses OLD dj
      d[r] = fmaf(bj, fmaf(n[r], sbj, -ai * aj), d[r]);
    }
    pd += __shfl_xor(pd, 1);
    pd += __shfl_xor(pd, 2);
    pd += __shfl_xor(pd, 4);
    pd += __shfl_xor(pd, 8);
    if (q == 0) djact_s[jl] = pd;

    {  // GEMV: all 1024 threads, 16 lanes per row, weights in regs
      float acc = 0.0f;
      #pragma unroll
      for (int k = 0; k < 2; ++k) {
        const float4 xv = *(const float4*)(xt_s + q * 8 + k * 4);
        acc = fmaf(winr[k].x, xv.x, acc); acc = fmaf(winr[k].y, xv.y, acc);
        acc = fmaf(winr[k].z, xv.z, acc); acc = fmaf(winr[k].w, xv.w, acc);
      }
      #pragma unroll
      for (int k = 0; k < 4; ++k) {
        const float4 av = *(const float4*)(a_s + q * 16 + k * 4);
        acc = fmaf(whr[k].x, av.x, acc); acc = fmaf(whr[k].y, av.y, acc);
        acc = fmaf(whr[k].z, av.z, acc); acc = fmaf(whr[k].w, av.w, acc);
      }
      acc += __shfl_xor(acc, 1);
      acc += __shfl_xor(acc, 2);
      acc += __shfl_xor(acc, 4);
      acc += __shfl_xor(acc, 8);
      if (q == 0) stat_s[jl] = acc + bias;
    }

    if (wv == 15 && t > 0) {   // output projection for t-1 (h_s = h(t-1)); 8 outputs
      const int o = ln >> 3, sub = ln & 7;
      float acc = 0.0f;
      #pragma unroll
      for (int k = 0; k < 8; ++k) {
        const float4 wvv = *(const float4*)(wos + o * 260 + sub * 32 + k * 4);
        const float4 hv  = *(const float4*)(h_s + sub * 32 + k * 4);
        acc = fmaf(wvv.x, hv.x, acc); acc = fmaf(wvv.y, hv.y, acc);
        acc = fmaf(wvv.z, hv.z, acc); acc = fmaf(wvv.w, hv.w, acc);
      }
      acc += __shfl_xor(acc, 1);
      acc += __shfl_xor(acc, 2);
      acc += __shfl_xor(acc, 4);
      if (sub == 0)
        out[HID_LIST_SZ + ((size_t)b * TT + (t - 1)) * NOUT + s * 8 + o] =
            20.0f * tanhf(acc);
    }
    __syncthreads();

    // ================ P2: h-update + publish, then RNG(t+1) ================
    if (tid < JS) {
      const float tmp  = stat_s[tid] + djact_s[tid];
      const float hnew = fmaf(r_al, tmp, r_om * h_s[s * JS + tid]) + hn * r_ns;
      __hip_atomic_store(&hpub[(par * BB + b) * NHID + s * JS + tid], hnew,
                         __ATOMIC_RELAXED, __HIP_MEMORY_SCOPE_AGENT);
    }
    if (tid == 0) {
      asm volatile("s_waitcnt vmcnt(0)" ::: "memory");   // h-slice visible first
      __hip_atomic_store(&flags[(b * BPS + s) * FLAG_STRIDE], (uint32_t)(t + 1),
                         __ATOMIC_RELAXED, __HIP_MEMORY_SCOPE_AGENT);
    }
    if (t + 1 < TT) {   // RNG for next step — hides the publish/flag latency
      const uint32_t k2a = __builtin_amdgcn_readfirstlane(keys_s[(t + 1) * 4 + 2]);
      const uint32_t k2b = __builtin_amdgcn_readfirstlane(keys_s[(t + 1) * 4 + 3]);
      #pragma unroll
      for (int r = 0; r < 16; ++r)
        n[r] = tf_normal(k2a, k2b, idxb + ((uint32_t)r << 12));
      if (tid < JS) {
        const uint32_t k1a = __builtin_amdgcn_readfirstlane(keys_s[(t + 1) * 4 + 0]);
        const uint32_t k1b = __builtin_amdgcn_readfirstlane(keys_s[(t + 1) * 4 + 1]);
        hn = tf_normal(k1a, k1b, hnidx);
      }
    }

    // ================ P3: poll flags, pull h(t), side jobs ================
    if (wv < 4) {
      if (ln == 0) SPIN(wv, t + 1);
      asm volatile("" ::: "memory");
      const float hv = __hip_atomic_load(&hpub[(par * BB + b) * NHID + wv * JS + ln],
                                         __ATOMIC_RELAXED, __HIP_MEMORY_SCOPE_AGENT);
      h_s[wv * JS + ln] = hv;
      a_s[wv * JS + ln] = tanhf(hv);
    } else if (wv < 8) {
      if (s == 0) {   // hidden_list (deduped: only s==0 writes)
        const int sl = wv - 4;
        const int k  = sl * JS + ln;
        if (ln == 0) SPIN(sl, t + 1);
        asm volatile("" ::: "memory");
        const float hv = __hip_atomic_load(&hpub[(par * BB + b) * NHID + k],
                                           __ATOMIC_RELAXED, __HIP_MEMORY_SCOPE_AGENT);
        out[((size_t)b * TT + t) * NHID + k] = hv;
        if (t == TT - 1)
          out[HID_LIST_SZ + OUT_LIST_SZ + (size_t)b * NHID + k] = hv;
      }
    } else if (wv < 10) {
      const int k = (wv - 8) * 64 + ln;            // 0..127: x prefetch
      if (t + 1 < TT) xt_s[k] = xin[((size_t)b * TT + t + 1) * NIN + k];
    }
    __syncthreads();
  }

  // ---- epilogue: output projection for t = 63 (h_s = h(63)) ----
  if (wv == 15) {
    const int o = ln >> 3, sub = ln & 7;
    float acc = 0.0f;
    #pragma unroll
    for (int k = 0; k < 8; ++k) {
      const float4 wvv = *(const float4*)(wos + o * 260 + sub * 32 + k * 4);
      const float4 hv  = *(const float4*)(h_s + sub * 32 + k * 4);
      acc = fmaf(wvv.x, hv.x, acc); acc = fmaf(wvv.y, hv.y, acc);
      acc = fmaf(wvv.z, hv.z, acc); acc = fmaf(wvv.w, hv.w, acc);
    }
    acc += __shfl_xor(acc, 1);
    acc += __shfl_xor(acc, 2);
    acc += __shfl_xor(acc, 4);
    if (sub == 0)
      out[HID_LIST_SZ + ((size_t)b * TT + (TT - 1)) * NOUT + s * 8 + o] =
          20.0f * tanhf(acc);
  }
}

extern "C" void kernel_launch(void* const* d_in, const int* in_sizes, int n_in,
                              void* d_out, int out_size, void* d_ws, size_t ws_size,
                              hipStream_t stream) {
  (void)in_sizes; (void)n_in; (void)out_size; (void)ws_size;
  const float* x     = (const float*)d_in[0];
  const float* h0    = (const float*)d_in[1];
  // d_in[2] = length (always 64)
  const float* w_in  = (const float*)d_in[3];
  const float* w_hh  = (const float*)d_in[4];
  const float* b_hh  = (const float*)d_in[5];
  const float* w_out = (const float*)d_in[6];
  const float* alpha = (const float*)d_in[7];
  const float* beta  = (const float*)d_in[8];
  float* out = (float*)d_out;

  hipMemsetAsync((char*)d_ws + FLAG_OFF, 0, FLAG_BYTES, stream);  // flag slots
  rnn_kernel<<<dim3(NBLK), dim3(NTHR), 0, stream>>>(
      x, h0, w_in, w_hh, b_hh, w_out, alpha, beta, out, (char*)d_ws);
}